// Round 2
// baseline (325.354 us; speedup 1.0000x reference)
//
#include <hip/hip_runtime.h>
#include <hip/hip_bf16.h>

#define L2E 1.4426950408889634f
#define LN2 0.6931471805599453f

__device__ __forceinline__ float fexp2(float x) {
#if __has_builtin(__builtin_amdgcn_exp2f)
    return __builtin_amdgcn_exp2f(x);
#else
    return exp2f(x);
#endif
}
__device__ __forceinline__ float flog2(float x) {
#if __has_builtin(__builtin_amdgcn_logf)
    return __builtin_amdgcn_logf(x);
#else
    return log2f(x);
#endif
}

// ---------------- workspace layout (in floats) ----------------
constexpr size_t P_A2 = 0;                   // 128*16 = 2048 : A*log2e, A=-exp(A_log)
// big arrays, feature-major [seq][feat][1024], seq = branch*8 + b, 32 seqs
constexpr size_t O_XN = 65536;               // 32*64*1024  = 2097152
constexpr size_t O_G  = O_XN + 2097152;      // 32*128*1024 = 4194304 (xi, later reused for y_ssm)
constexpr size_t O_Z  = O_G  + 4194304;      // 4194304
constexpr size_t O_XC = O_Z  + 4194304;      // 4194304
constexpr size_t O_DT = O_XC + 4194304;      // 4194304
constexpr size_t O_BM = O_DT + 4194304;      // 32*16*1024 = 524288
constexpr size_t O_CM = O_BM + 524288;       // 524288
constexpr size_t O_HP = O_CM + 524288;       // 32*8*2*2048 = 1048576 (per-chunk P and h_end)
// total = 21,037,056 floats = 84.1 MB

// ---------------- K0: A transform ----------------
__global__ void k0_a2(const float* __restrict__ alog, float* __restrict__ ws)
{
    int i = blockIdx.x * 256 + threadIdx.x;
    if (i < 2048) { ws[P_A2 + i] = -fexp2(alog[i] * L2E) * L2E; }
}

// ---------------- K1: LayerNorm + in-projection (64 -> 256) ----------------
// grid 512 = 32 seq * 16 p-tiles, block 256 = 64 p-lanes * 4 waves (each wave: 64 j's)
__global__ __launch_bounds__(256) void k1_ln_inproj(const float* __restrict__ x0,
                                                    const float* __restrict__ x1,
                                                    const float* __restrict__ x2,
                                                    const float* __restrict__ x3,
                                                    const float* __restrict__ win,
                                                    const float* __restrict__ g1, const float* __restrict__ be1,
                                                    const float* __restrict__ g2, const float* __restrict__ be2,
                                                    const float* __restrict__ g3, const float* __restrict__ be3,
                                                    const float* __restrict__ g4, const float* __restrict__ be4,
                                                    float* __restrict__ ws)
{
    int bid = blockIdx.x;
    int seq = bid >> 4, pt = bid & 15;
    int branch = seq >> 3, b = seq & 7;
    int lane = threadIdx.x & 63, wq = threadIdx.x >> 6;
    int p = pt * 64 + lane;
    const float* xin = (branch==0)?x0:(branch==1)?x1:(branch==2)?x2:x3;
    const float* xb = xin + (size_t)b * 64 * 1024;
    const float* gam = (branch==0)?g1:(branch==1)?g2:(branch==2)?g3:g4;
    const float* bet = (branch==0)?be1:(branch==1)?be2:(branch==2)?be3:be4;

    float xr[64];
    float sum = 0.f, sq = 0.f;
#pragma unroll
    for (int c = 0; c < 64; ++c) {
        float v = xb[c * 1024 + p];
        xr[c] = v; sum += v; sq += v * v;
    }
    float mean = sum * (1.f/64.f);
    float var  = sq * (1.f/64.f) - mean * mean;
    float rs   = rsqrtf(var + 1e-5f);
#pragma unroll
    for (int c = 0; c < 64; ++c)
        xr[c] = (xr[c] - mean) * rs * gam[c] + bet[c];

    if (wq == 0) {
        float* xn = ws + O_XN + (size_t)seq * 64 * 1024;
#pragma unroll
        for (int c = 0; c < 64; ++c) xn[(size_t)c * 1024 + p] = xr[c];
    }

    float* xi = ws + O_G + (size_t)seq * 128 * 1024;
    float* zz = ws + O_Z + (size_t)seq * 128 * 1024;
    for (int jj = 0; jj < 64; ++jj) {
        int j = wq * 64 + jj;
        const float* wrow = win + (size_t)j * 64;   // wave-uniform -> s_load broadcast
        float acc = 0.f;
#pragma unroll
        for (int c = 0; c < 64; ++c) acc += xr[c] * wrow[c];
        if (j < 128) xi[(size_t)j * 1024 + p] = acc;
        else         zz[(size_t)(j - 128) * 1024 + p] = acc;
    }
}

// ---------------- K2: causal conv4 + SiLU + x-proj(128->36) + dt ----------------
// grid 512 = 32 seq * 16 p-tiles, block 256 = 64 p-lanes * 4 waves (each wave: 32 d's)
__global__ __launch_bounds__(256) void k2_conv_proj(const float* __restrict__ wconv,
                                                    const float* __restrict__ bconv,
                                                    const float* __restrict__ wxp,
                                                    const float* __restrict__ wdt,
                                                    const float* __restrict__ bdt,
                                                    float* __restrict__ ws)
{
    __shared__ float s_red[4 * 36 * 64];
    __shared__ float s_dtp[4 * 64];
    int bid = blockIdx.x;
    int seq = bid >> 4, pt = bid & 15;
    int lane = threadIdx.x & 63, wq = threadIdx.x >> 6;
    int p = pt * 64 + lane;
    const float* xi = ws + O_G  + (size_t)seq * 128 * 1024;
    float*       xc = ws + O_XC + (size_t)seq * 128 * 1024;

    float acc36[36];
#pragma unroll
    for (int j = 0; j < 36; ++j) acc36[j] = 0.f;

    for (int dd = 0; dd < 32; ++dd) {
        int d = wq * 32 + dd;
        const float* row = xi + (size_t)d * 1024;
        const float* wc = wconv + (size_t)d * 4;
        float v = bconv[d];
#pragma unroll
        for (int k = 0; k < 4; ++k) {
            int q = p - 3 + k;
            float xv = (q >= 0) ? row[q] : 0.f;
            v += xv * wc[k];
        }
        float sg = 1.f / (1.f + fexp2(-v * L2E));   // silu
        v = v * sg;
        xc[(size_t)d * 1024 + p] = v;
#pragma unroll
        for (int j = 0; j < 36; ++j) acc36[j] += v * wxp[j * 128 + d];
    }
    for (int j = 0; j < 36; ++j) s_red[(wq * 36 + j) * 64 + lane] = acc36[j];
    __syncthreads();
    if (wq == 0) {
        float* Bm = ws + O_BM + (size_t)seq * 16 * 1024;
        float* Cm = ws + O_CM + (size_t)seq * 16 * 1024;
        for (int j = 0; j < 36; ++j) {
            float t = s_red[j*64+lane] + s_red[(36+j)*64+lane] + s_red[(72+j)*64+lane] + s_red[(108+j)*64+lane];
            if (j < 4)       s_dtp[j * 64 + lane] = t;
            else if (j < 20) Bm[(size_t)(j - 4)  * 1024 + p] = t;
            else             Cm[(size_t)(j - 20) * 1024 + p] = t;
        }
    }
    __syncthreads();
    float d0 = s_dtp[0*64+lane], d1 = s_dtp[1*64+lane], d2 = s_dtp[2*64+lane], d3 = s_dtp[3*64+lane];
    float* dtg = ws + O_DT + (size_t)seq * 128 * 1024;
    for (int dd = 0; dd < 32; ++dd) {
        int d = wq * 32 + dd;
        const float* wd = wdt + (size_t)d * 4;
        float t = bdt[d] + d0*wd[0] + d1*wd[1] + d2*wd[2] + d3*wd[3];
        float sp = (t > 20.f) ? t : LN2 * flog2(1.f + fexp2(t * L2E));  // softplus
        dtg[(size_t)d * 1024 + p] = sp;
    }
}

// ---------------- K3: chunk-parallel selective scan ----------------
// 8 chunks of 128 steps; grid 256 = 32 seq * 8 chunks, block 256.
// thread -> d-pair (tid>>2)*2, s-quad (tid&3)*4 : 8 states/thread.
#define SCAN_SC 32

// phase A: local scan with h0=0; emit per-chunk decay product P and local end-state E
__global__ __launch_bounds__(256) void k3a_scan(float* __restrict__ ws)
{
    __shared__ float s_dt[128 * 33];
    __shared__ float s_xc[128 * 33];
    __shared__ __align__(16) float s_B[SCAN_SC * 16];
    int bid = blockIdx.x;
    int seq = bid >> 3, ch = bid & 7;
    int tid = threadIdx.x;
    int dp = tid >> 2, sq = tid & 3;
    int d0 = dp * 2, s0 = sq * 4;
    const float* dtg = ws + O_DT + (size_t)seq * 128 * 1024;
    const float* xcg = ws + O_XC + (size_t)seq * 128 * 1024;
    const float* Bmg = ws + O_BM + (size_t)seq * 16 * 1024;

    float h[8], P[8], a2[8];
#pragma unroll
    for (int i = 0; i < 8; ++i) { h[i] = 0.f; P[i] = 1.f; }
#pragma unroll
    for (int dd = 0; dd < 2; ++dd)
#pragma unroll
        for (int ss = 0; ss < 4; ++ss)
            a2[dd*4+ss] = ws[P_A2 + (size_t)(d0+dd) * 16 + s0 + ss];

    int l0 = ch * 128;
    for (int scb = 0; scb < 128 / SCAN_SC; ++scb) {
        int lb = l0 + scb * SCAN_SC;
        for (int idx = tid; idx < 128 * SCAN_SC; idx += 256) {
            int d = idx >> 5, li = idx & 31;
            s_dt[d*33+li] = dtg[(size_t)d * 1024 + lb + li];
            s_xc[d*33+li] = xcg[(size_t)d * 1024 + lb + li];
        }
        for (int idx = tid; idx < 16 * SCAN_SC; idx += 256) {
            int s = idx >> 5, li = idx & 31;
            s_B[li*16+s] = Bmg[(size_t)s * 1024 + lb + li];
        }
        __syncthreads();
        for (int li = 0; li < SCAN_SC; ++li) {
            float dt0 = s_dt[d0*33+li], dt1 = s_dt[(d0+1)*33+li];
            float xc0 = s_xc[d0*33+li], xc1 = s_xc[(d0+1)*33+li];
            float dx0 = dt0 * xc0, dx1 = dt1 * xc1;
            float4 Bv = *(const float4*)&s_B[li*16 + s0];
            float bv[4] = {Bv.x, Bv.y, Bv.z, Bv.w};
#pragma unroll
            for (int ss = 0; ss < 4; ++ss) {
                float e0 = fexp2(dt0 * a2[ss]);
                h[ss] = e0 * h[ss] + dx0 * bv[ss];
                P[ss] *= e0;
                float e1 = fexp2(dt1 * a2[4+ss]);
                h[4+ss] = e1 * h[4+ss] + dx1 * bv[ss];
                P[4+ss] *= e1;
            }
        }
        __syncthreads();
    }
    float* hp = ws + O_HP + (size_t)(seq * 8 + ch) * 4096;
#pragma unroll
    for (int dd = 0; dd < 2; ++dd)
#pragma unroll
        for (int ss = 0; ss < 4; ++ss) {
            hp[(d0+dd)*16 + s0 + ss]        = P[dd*4+ss];
            hp[2048 + (d0+dd)*16 + s0 + ss] = h[dd*4+ss];
        }
}

// phase C: compose prefix h_init from chunk summaries, rescan emitting y_ssm (into O_G)
__global__ __launch_bounds__(256) void k3c_scan_y(float* __restrict__ ws)
{
    __shared__ float s_dt[128 * 33];
    __shared__ float s_xc[128 * 33];
    __shared__ float s_y[128 * 33];
    __shared__ __align__(16) float s_B[SCAN_SC * 16];
    __shared__ __align__(16) float s_C[SCAN_SC * 16];
    int bid = blockIdx.x;
    int seq = bid >> 3, ch = bid & 7;
    int tid = threadIdx.x;
    int dp = tid >> 2, sq = tid & 3;
    int d0 = dp * 2, s0 = sq * 4;
    const float* dtg = ws + O_DT + (size_t)seq * 128 * 1024;
    const float* xcg = ws + O_XC + (size_t)seq * 128 * 1024;
    const float* Bmg = ws + O_BM + (size_t)seq * 16 * 1024;
    const float* Cmg = ws + O_CM + (size_t)seq * 16 * 1024;
    float*       gg  = ws + O_G  + (size_t)seq * 128 * 1024;  // y_ssm (xi region, dead)

    float h[8], a2[8];
#pragma unroll
    for (int i = 0; i < 8; ++i) h[i] = 0.f;
    const float* hpb = ws + O_HP + (size_t)seq * 8 * 4096;
    for (int c = 0; c < ch; ++c) {
        const float* hp = hpb + (size_t)c * 4096;
#pragma unroll
        for (int dd = 0; dd < 2; ++dd) {
            float4 Pv = *(const float4*)&hp[(d0+dd)*16 + s0];
            float4 Ev = *(const float4*)&hp[2048 + (d0+dd)*16 + s0];
            h[dd*4+0] = Pv.x * h[dd*4+0] + Ev.x;
            h[dd*4+1] = Pv.y * h[dd*4+1] + Ev.y;
            h[dd*4+2] = Pv.z * h[dd*4+2] + Ev.z;
            h[dd*4+3] = Pv.w * h[dd*4+3] + Ev.w;
        }
    }
#pragma unroll
    for (int dd = 0; dd < 2; ++dd)
#pragma unroll
        for (int ss = 0; ss < 4; ++ss)
            a2[dd*4+ss] = ws[P_A2 + (size_t)(d0+dd) * 16 + s0 + ss];

    int l0 = ch * 128;
    for (int scb = 0; scb < 128 / SCAN_SC; ++scb) {
        int lb = l0 + scb * SCAN_SC;
        for (int idx = tid; idx < 128 * SCAN_SC; idx += 256) {
            int d = idx >> 5, li = idx & 31;
            s_dt[d*33+li] = dtg[(size_t)d * 1024 + lb + li];
            s_xc[d*33+li] = xcg[(size_t)d * 1024 + lb + li];
        }
        for (int idx = tid; idx < 16 * SCAN_SC; idx += 256) {
            int s = idx >> 5, li = idx & 31;
            s_B[li*16+s] = Bmg[(size_t)s * 1024 + lb + li];
            s_C[li*16+s] = Cmg[(size_t)s * 1024 + lb + li];
        }
        __syncthreads();
        for (int li = 0; li < SCAN_SC; ++li) {
            float dt0 = s_dt[d0*33+li], dt1 = s_dt[(d0+1)*33+li];
            float xc0 = s_xc[d0*33+li], xc1 = s_xc[(d0+1)*33+li];
            float dx0 = dt0 * xc0, dx1 = dt1 * xc1;
            float4 Bv = *(const float4*)&s_B[li*16 + s0];
            float4 Cv = *(const float4*)&s_C[li*16 + s0];
            float bv[4] = {Bv.x, Bv.y, Bv.z, Bv.w};
            float cv[4] = {Cv.x, Cv.y, Cv.z, Cv.w};
            float acc0 = 0.f, acc1 = 0.f;
#pragma unroll
            for (int ss = 0; ss < 4; ++ss) {
                float e0 = fexp2(dt0 * a2[ss]);
                h[ss] = e0 * h[ss] + dx0 * bv[ss];
                acc0 += h[ss] * cv[ss];
                float e1 = fexp2(dt1 * a2[4+ss]);
                h[4+ss] = e1 * h[4+ss] + dx1 * bv[ss];
                acc1 += h[4+ss] * cv[ss];
            }
            acc0 += __shfl_xor(acc0, 1); acc0 += __shfl_xor(acc0, 2);
            acc1 += __shfl_xor(acc1, 1); acc1 += __shfl_xor(acc1, 2);
            if (sq == 0) {
                s_y[d0*33+li]     = acc0;
                s_y[(d0+1)*33+li] = acc1;
            }
        }
        __syncthreads();
        for (int idx = tid; idx < 128 * SCAN_SC; idx += 256) {
            int d = idx >> 5, li = idx & 31;
            gg[(size_t)d * 1024 + lb + li] = s_y[d*33+li];
        }
    }
}

// ---------------- K4: gate + out-projection (128 -> 64) + skip, f32 out ----------------
// grid 512 = 32 seq * 16 p-tiles, block 256 = 64 p-lanes * 4 waves (each wave: 16 c's)
__global__ __launch_bounds__(256) void k4_out(const float* __restrict__ ws,
                                              const float* __restrict__ dpar,
                                              const float* __restrict__ woutp,
                                              const float* __restrict__ skipp,
                                              float* __restrict__ out)
{
    int bid = blockIdx.x;
    int seq = bid >> 4, pt = bid & 15;
    int branch = seq >> 3, b = seq & 7;
    int lane = threadIdx.x & 63, cq = threadIdx.x >> 6;
    int p = pt * 64 + lane;
    const float* ys = ws + O_G  + (size_t)seq * 128 * 1024;
    const float* zz = ws + O_Z  + (size_t)seq * 128 * 1024;
    const float* xc = ws + O_XC + (size_t)seq * 128 * 1024;
    const float* wout = woutp + (size_t)cq * 16 * 128;

    float acc[16];
#pragma unroll
    for (int c = 0; c < 16; ++c) acc[c] = 0.f;
    for (int d = 0; d < 128; ++d) {
        float yv  = ys[(size_t)d * 1024 + p];
        float zv  = zz[(size_t)d * 1024 + p];
        float xcv = xc[(size_t)d * 1024 + p];
        float g = (yv + dpar[d] * xcv) * (zv / (1.f + fexp2(-zv * L2E)));
#pragma unroll
        for (int c = 0; c < 16; ++c) acc[c] += g * wout[c * 128 + d];
    }
    float skip = skipp[0];
    const float* xn = ws + O_XN + (size_t)seq * 64 * 1024;
    float* ob = out + ((size_t)b * 256 + branch * 64 + cq * 16) * 1024;
#pragma unroll
    for (int c = 0; c < 16; ++c) {
        float o = acc[c] + skip * xn[(size_t)(cq * 16 + c) * 1024 + p];
        ob[(size_t)c * 1024 + p] = o;
    }
}

// ---------------- launch ----------------
extern "C" void kernel_launch(void* const* d_in, const int* in_sizes, int n_in,
                              void* d_out, int out_size, void* d_ws, size_t ws_size,
                              hipStream_t stream) {
    float* ws = (float*)d_ws;
    auto f = [&](int i) { return (const float*)d_in[i]; };
    hipLaunchKernelGGL(k0_a2, dim3(8), dim3(256), 0, stream, f(19), ws);
    hipLaunchKernelGGL(k1_ln_inproj, dim3(512), dim3(256), 0, stream,
        f(0), f(1), f(2), f(3), f(13),
        f(4), f(5), f(6), f(7), f(8), f(9), f(10), f(11), ws);
    hipLaunchKernelGGL(k2_conv_proj, dim3(512), dim3(256), 0, stream,
        f(14), f(15), f(16), f(17), f(18), ws);
    hipLaunchKernelGGL(k3a_scan, dim3(256), dim3(256), 0, stream, ws);
    hipLaunchKernelGGL(k3c_scan_y, dim3(256), dim3(256), 0, stream, ws);
    hipLaunchKernelGGL(k4_out, dim3(512), dim3(256), 0, stream, ws, f(20), f(21), f(12),
        (float*)d_out);
}

// Round 3
// 294.106 us; speedup vs baseline: 1.1062x; 1.1062x over previous
//
#include <hip/hip_runtime.h>
#include <hip/hip_bf16.h>

#define L2E 1.4426950408889634f
#define LN2 0.6931471805599453f

__device__ __forceinline__ float fexp2(float x) {
#if __has_builtin(__builtin_amdgcn_exp2f)
    return __builtin_amdgcn_exp2f(x);
#else
    return exp2f(x);
#endif
}
__device__ __forceinline__ float flog2(float x) {
#if __has_builtin(__builtin_amdgcn_logf)
    return __builtin_amdgcn_logf(x);
#else
    return log2f(x);
#endif
}
__device__ __forceinline__ int uniform(int x) { return __builtin_amdgcn_readfirstlane(x); }

// ---------------- workspace layout (in floats) ----------------
// big arrays, feature-major [seq][feat][1024], seq = branch*8 + b, 32 seqs
constexpr size_t O_XN = 0;                   // 32*64*1024  = 2097152
constexpr size_t O_G  = O_XN + 2097152;      // 32*128*1024 = 4194304 (xi, later reused for y_ssm)
constexpr size_t O_Z  = O_G  + 4194304;      // 4194304
constexpr size_t O_XC = O_Z  + 4194304;      // 4194304
constexpr size_t O_DT = O_XC + 4194304;      // 4194304
constexpr size_t O_BM = O_DT + 4194304;      // 32*16*1024 = 524288
constexpr size_t O_CM = O_BM + 524288;       // 524288
constexpr size_t O_HP = O_CM + 524288;       // 32*8*2*2048 = 1048576 (per-chunk P and h_end)

// ---------------- K1: LayerNorm + in-projection (64 -> 256) ----------------
// grid 1024 = 32 seq * 32 subtiles (16 p-tiles x 2 j-halves), block 256.
// Each wave: 64 p-lanes, 32 output j's (rows scalar via readfirstlane -> s_load).
__global__ __launch_bounds__(256) void k1_ln_inproj(const float* __restrict__ x0,
                                                    const float* __restrict__ x1,
                                                    const float* __restrict__ x2,
                                                    const float* __restrict__ x3,
                                                    const float* __restrict__ win,
                                                    const float* __restrict__ g1, const float* __restrict__ be1,
                                                    const float* __restrict__ g2, const float* __restrict__ be2,
                                                    const float* __restrict__ g3, const float* __restrict__ be3,
                                                    const float* __restrict__ g4, const float* __restrict__ be4,
                                                    float* __restrict__ ws)
{
    int bid = blockIdx.x;
    int seq = bid >> 5, sub = bid & 31;
    int pt = sub >> 1, half = sub & 1;
    int branch = seq >> 3, b = seq & 7;
    int lane = threadIdx.x & 63;
    int wq = uniform(threadIdx.x >> 6);
    int p = pt * 64 + lane;
    const float* xin = (branch==0)?x0:(branch==1)?x1:(branch==2)?x2:x3;
    const float* xb = xin + (size_t)b * 64 * 1024;
    const float* gam = (branch==0)?g1:(branch==1)?g2:(branch==2)?g3:g4;
    const float* bet = (branch==0)?be1:(branch==1)?be2:(branch==2)?be3:be4;

    float xr[64];
    float sum = 0.f, sq = 0.f;
#pragma unroll
    for (int c = 0; c < 64; ++c) {
        float v = xb[c * 1024 + p];
        xr[c] = v; sum += v; sq += v * v;
    }
    float mean = sum * (1.f/64.f);
    float var  = sq * (1.f/64.f) - mean * mean;
    float rs   = rsqrtf(var + 1e-5f);
#pragma unroll
    for (int c = 0; c < 64; ++c)
        xr[c] = (xr[c] - mean) * rs * gam[c] + bet[c];

    if (half == 0 && wq == 0) {
        float* xn = ws + O_XN + (size_t)seq * 64 * 1024;
#pragma unroll
        for (int c = 0; c < 64; ++c) xn[(size_t)c * 1024 + p] = xr[c];
    }

    float* xi = ws + O_G + (size_t)seq * 128 * 1024;
    float* zz = ws + O_Z + (size_t)seq * 128 * 1024;
    int jbase = half * 128 + wq * 32;
    for (int jj = 0; jj < 32; ++jj) {
        int j = jbase + jj;                          // wave-uniform (scalar)
        const float* wrow = win + (size_t)j * 64;    // scalar pointer -> s_load
        float acc = 0.f;
#pragma unroll
        for (int c = 0; c < 64; ++c) acc += xr[c] * wrow[c];
        if (j < 128) xi[(size_t)j * 1024 + p] = acc;
        else         zz[(size_t)(j - 128) * 1024 + p] = acc;
    }
}

// ---------------- K2: causal conv4 + SiLU + x-proj(128->36) + dt ----------------
// grid 512 = 32 seq * 16 p-tiles, block 256 = 64 p-lanes * 4 waves (each wave: 32 d's)
__global__ __launch_bounds__(256) void k2_conv_proj(const float* __restrict__ wconv,
                                                    const float* __restrict__ bconv,
                                                    const float* __restrict__ wxp,
                                                    const float* __restrict__ wdt,
                                                    const float* __restrict__ bdt,
                                                    float* __restrict__ ws)
{
    __shared__ float s_red[4 * 36 * 64];
    __shared__ float s_dtp[4 * 64];
    int bid = blockIdx.x;
    int seq = bid >> 4, pt = bid & 15;
    int lane = threadIdx.x & 63;
    int wq = uniform(threadIdx.x >> 6);
    int p = pt * 64 + lane;
    const float* xi = ws + O_G  + (size_t)seq * 128 * 1024;
    float*       xc = ws + O_XC + (size_t)seq * 128 * 1024;

    float acc36[36];
#pragma unroll
    for (int j = 0; j < 36; ++j) acc36[j] = 0.f;

    for (int dd = 0; dd < 32; ++dd) {
        int d = wq * 32 + dd;                       // scalar
        const float* row = xi + (size_t)d * 1024;
        const float* wc = wconv + (size_t)d * 4;    // scalar -> s_load
        float v = bconv[d];
#pragma unroll
        for (int k = 0; k < 4; ++k) {
            int q = p - 3 + k;
            float xv = (q >= 0) ? row[q] : 0.f;
            v += xv * wc[k];
        }
        float sg = 1.f / (1.f + fexp2(-v * L2E));   // silu
        v = v * sg;
        xc[(size_t)d * 1024 + p] = v;
#pragma unroll
        for (int j = 0; j < 36; ++j) acc36[j] += v * wxp[j * 128 + d];   // scalar weights
    }
    for (int j = 0; j < 36; ++j) s_red[(wq * 36 + j) * 64 + lane] = acc36[j];
    __syncthreads();
    if (threadIdx.x < 64) {
        float* Bm = ws + O_BM + (size_t)seq * 16 * 1024;
        float* Cm = ws + O_CM + (size_t)seq * 16 * 1024;
        for (int j = 0; j < 36; ++j) {
            float t = s_red[j*64+lane] + s_red[(36+j)*64+lane] + s_red[(72+j)*64+lane] + s_red[(108+j)*64+lane];
            if (j < 4)       s_dtp[j * 64 + lane] = t;
            else if (j < 20) Bm[(size_t)(j - 4)  * 1024 + p] = t;
            else             Cm[(size_t)(j - 20) * 1024 + p] = t;
        }
    }
    __syncthreads();
    float d0 = s_dtp[0*64+lane], d1 = s_dtp[1*64+lane], d2 = s_dtp[2*64+lane], d3 = s_dtp[3*64+lane];
    float* dtg = ws + O_DT + (size_t)seq * 128 * 1024;
    for (int dd = 0; dd < 32; ++dd) {
        int d = wq * 32 + dd;                       // scalar
        const float* wd = wdt + (size_t)d * 4;      // s_load
        float t = bdt[d] + d0*wd[0] + d1*wd[1] + d2*wd[2] + d3*wd[3];
        float sp = (t > 20.f) ? t : LN2 * flog2(1.f + fexp2(t * L2E));  // softplus
        dtg[(size_t)d * 1024 + p] = sp;
    }
}

// ---------------- K3: chunk-parallel selective scan ----------------
// 8 chunks of 128 steps; grid 256 = 32 seq * 8 chunks, block 256.
// thread -> d-pair (tid>>2)*2, s-quad (tid&3)*4 : 8 states/thread.
#define SCAN_SC 32

__device__ __forceinline__ void load_a2(const float* alog, int d0, int s0, float* a2) {
#pragma unroll
    for (int dd = 0; dd < 2; ++dd)
#pragma unroll
        for (int ss = 0; ss < 4; ++ss) {
            float a = alog[(size_t)(d0+dd) * 16 + s0 + ss];
            a2[dd*4+ss] = -fexp2(a * L2E) * L2E;
        }
}

// phase A: local scan with h0=0; emit per-chunk decay product P and local end-state E
__global__ __launch_bounds__(256) void k3a_scan(const float* __restrict__ alog, float* __restrict__ ws)
{
    __shared__ float s_dt[128 * 33];
    __shared__ float s_xc[128 * 33];
    __shared__ __align__(16) float s_B[SCAN_SC * 16];
    int bid = blockIdx.x;
    int seq = bid >> 3, ch = bid & 7;
    int tid = threadIdx.x;
    int dp = tid >> 2, sq = tid & 3;
    int d0 = dp * 2, s0 = sq * 4;
    const float* dtg = ws + O_DT + (size_t)seq * 128 * 1024;
    const float* xcg = ws + O_XC + (size_t)seq * 128 * 1024;
    const float* Bmg = ws + O_BM + (size_t)seq * 16 * 1024;

    float h[8], P[8], a2[8];
#pragma unroll
    for (int i = 0; i < 8; ++i) { h[i] = 0.f; P[i] = 1.f; }
    load_a2(alog, d0, s0, a2);

    int l0 = ch * 128;
    for (int scb = 0; scb < 128 / SCAN_SC; ++scb) {
        int lb = l0 + scb * SCAN_SC;
        for (int idx = tid; idx < 128 * SCAN_SC; idx += 256) {
            int d = idx >> 5, li = idx & 31;
            s_dt[d*33+li] = dtg[(size_t)d * 1024 + lb + li];
            s_xc[d*33+li] = xcg[(size_t)d * 1024 + lb + li];
        }
        for (int idx = tid; idx < 16 * SCAN_SC; idx += 256) {
            int s = idx >> 5, li = idx & 31;
            s_B[li*16+s] = Bmg[(size_t)s * 1024 + lb + li];
        }
        __syncthreads();
        for (int li = 0; li < SCAN_SC; ++li) {
            float dt0 = s_dt[d0*33+li], dt1 = s_dt[(d0+1)*33+li];
            float xc0 = s_xc[d0*33+li], xc1 = s_xc[(d0+1)*33+li];
            float dx0 = dt0 * xc0, dx1 = dt1 * xc1;
            float4 Bv = *(const float4*)&s_B[li*16 + s0];
            float bv[4] = {Bv.x, Bv.y, Bv.z, Bv.w};
#pragma unroll
            for (int ss = 0; ss < 4; ++ss) {
                float e0 = fexp2(dt0 * a2[ss]);
                h[ss] = e0 * h[ss] + dx0 * bv[ss];
                P[ss] *= e0;
                float e1 = fexp2(dt1 * a2[4+ss]);
                h[4+ss] = e1 * h[4+ss] + dx1 * bv[ss];
                P[4+ss] *= e1;
            }
        }
        __syncthreads();
    }
    float* hp = ws + O_HP + (size_t)(seq * 8 + ch) * 4096;
#pragma unroll
    for (int dd = 0; dd < 2; ++dd)
#pragma unroll
        for (int ss = 0; ss < 4; ++ss) {
            hp[(d0+dd)*16 + s0 + ss]        = P[dd*4+ss];
            hp[2048 + (d0+dd)*16 + s0 + ss] = h[dd*4+ss];
        }
}

// phase C: compose prefix h_init from chunk summaries, rescan emitting y_ssm (into O_G)
__global__ __launch_bounds__(256) void k3c_scan_y(const float* __restrict__ alog, float* __restrict__ ws)
{
    __shared__ float s_dt[128 * 33];
    __shared__ float s_xc[128 * 33];
    __shared__ float s_y[128 * 33];
    __shared__ __align__(16) float s_B[SCAN_SC * 16];
    __shared__ __align__(16) float s_C[SCAN_SC * 16];
    int bid = blockIdx.x;
    int seq = bid >> 3, ch = bid & 7;
    int tid = threadIdx.x;
    int dp = tid >> 2, sq = tid & 3;
    int d0 = dp * 2, s0 = sq * 4;
    const float* dtg = ws + O_DT + (size_t)seq * 128 * 1024;
    const float* xcg = ws + O_XC + (size_t)seq * 128 * 1024;
    const float* Bmg = ws + O_BM + (size_t)seq * 16 * 1024;
    const float* Cmg = ws + O_CM + (size_t)seq * 16 * 1024;
    float*       gg  = ws + O_G  + (size_t)seq * 128 * 1024;  // y_ssm (xi region, dead)

    float h[8], a2[8];
#pragma unroll
    for (int i = 0; i < 8; ++i) h[i] = 0.f;
    const float* hpb = ws + O_HP + (size_t)seq * 8 * 4096;
    for (int c = 0; c < ch; ++c) {
        const float* hp = hpb + (size_t)c * 4096;
#pragma unroll
        for (int dd = 0; dd < 2; ++dd) {
            float4 Pv = *(const float4*)&hp[(d0+dd)*16 + s0];
            float4 Ev = *(const float4*)&hp[2048 + (d0+dd)*16 + s0];
            h[dd*4+0] = Pv.x * h[dd*4+0] + Ev.x;
            h[dd*4+1] = Pv.y * h[dd*4+1] + Ev.y;
            h[dd*4+2] = Pv.z * h[dd*4+2] + Ev.z;
            h[dd*4+3] = Pv.w * h[dd*4+3] + Ev.w;
        }
    }
    load_a2(alog, d0, s0, a2);

    int l0 = ch * 128;
    for (int scb = 0; scb < 128 / SCAN_SC; ++scb) {
        int lb = l0 + scb * SCAN_SC;
        for (int idx = tid; idx < 128 * SCAN_SC; idx += 256) {
            int d = idx >> 5, li = idx & 31;
            s_dt[d*33+li] = dtg[(size_t)d * 1024 + lb + li];
            s_xc[d*33+li] = xcg[(size_t)d * 1024 + lb + li];
        }
        for (int idx = tid; idx < 16 * SCAN_SC; idx += 256) {
            int s = idx >> 5, li = idx & 31;
            s_B[li*16+s] = Bmg[(size_t)s * 1024 + lb + li];
            s_C[li*16+s] = Cmg[(size_t)s * 1024 + lb + li];
        }
        __syncthreads();
        for (int li = 0; li < SCAN_SC; ++li) {
            float dt0 = s_dt[d0*33+li], dt1 = s_dt[(d0+1)*33+li];
            float xc0 = s_xc[d0*33+li], xc1 = s_xc[(d0+1)*33+li];
            float dx0 = dt0 * xc0, dx1 = dt1 * xc1;
            float4 Bv = *(const float4*)&s_B[li*16 + s0];
            float4 Cv = *(const float4*)&s_C[li*16 + s0];
            float bv[4] = {Bv.x, Bv.y, Bv.z, Bv.w};
            float cv[4] = {Cv.x, Cv.y, Cv.z, Cv.w};
            float acc0 = 0.f, acc1 = 0.f;
#pragma unroll
            for (int ss = 0; ss < 4; ++ss) {
                float e0 = fexp2(dt0 * a2[ss]);
                h[ss] = e0 * h[ss] + dx0 * bv[ss];
                acc0 += h[ss] * cv[ss];
                float e1 = fexp2(dt1 * a2[4+ss]);
                h[4+ss] = e1 * h[4+ss] + dx1 * bv[ss];
                acc1 += h[4+ss] * cv[ss];
            }
            acc0 += __shfl_xor(acc0, 1); acc0 += __shfl_xor(acc0, 2);
            acc1 += __shfl_xor(acc1, 1); acc1 += __shfl_xor(acc1, 2);
            if (sq == 0) {
                s_y[d0*33+li]     = acc0;
                s_y[(d0+1)*33+li] = acc1;
            }
        }
        __syncthreads();
        for (int idx = tid; idx < 128 * SCAN_SC; idx += 256) {
            int d = idx >> 5, li = idx & 31;
            gg[(size_t)d * 1024 + lb + li] = s_y[d*33+li];
        }
    }
}

// ---------------- K4: gate + out-projection (128 -> 64) + skip, f32 out ----------------
// grid 512 = 32 seq * 16 p-tiles, block 256 = 64 p-lanes * 4 waves (each wave: 16 c's)
__global__ __launch_bounds__(256) void k4_out(const float* __restrict__ ws,
                                              const float* __restrict__ dpar,
                                              const float* __restrict__ woutp,
                                              const float* __restrict__ skipp,
                                              float* __restrict__ out)
{
    int bid = blockIdx.x;
    int seq = bid >> 4, pt = bid & 15;
    int branch = seq >> 3, b = seq & 7;
    int lane = threadIdx.x & 63;
    int cq = uniform(threadIdx.x >> 6);
    int p = pt * 64 + lane;
    const float* ys = ws + O_G  + (size_t)seq * 128 * 1024;
    const float* zz = ws + O_Z  + (size_t)seq * 128 * 1024;
    const float* xc = ws + O_XC + (size_t)seq * 128 * 1024;
    const float* wout = woutp + (size_t)cq * 16 * 128;       // scalar base

    float acc[16];
#pragma unroll
    for (int c = 0; c < 16; ++c) acc[c] = 0.f;
    for (int d = 0; d < 128; ++d) {
        float yv  = ys[(size_t)d * 1024 + p];
        float zv  = zz[(size_t)d * 1024 + p];
        float xcv = xc[(size_t)d * 1024 + p];
        float g = (yv + dpar[d] * xcv) * (zv / (1.f + fexp2(-zv * L2E)));
#pragma unroll
        for (int c = 0; c < 16; ++c) acc[c] += g * wout[c * 128 + d];   // scalar weights
    }
    float skip = skipp[0];
    const float* xn = ws + O_XN + (size_t)seq * 64 * 1024;
    float* ob = out + ((size_t)b * 256 + branch * 64 + cq * 16) * 1024;
#pragma unroll
    for (int c = 0; c < 16; ++c) {
        float o = acc[c] + skip * xn[(size_t)(cq * 16 + c) * 1024 + p];
        ob[(size_t)c * 1024 + p] = o;
    }
}

// ---------------- launch ----------------
extern "C" void kernel_launch(void* const* d_in, const int* in_sizes, int n_in,
                              void* d_out, int out_size, void* d_ws, size_t ws_size,
                              hipStream_t stream) {
    float* ws = (float*)d_ws;
    auto f = [&](int i) { return (const float*)d_in[i]; };
    hipLaunchKernelGGL(k1_ln_inproj, dim3(1024), dim3(256), 0, stream,
        f(0), f(1), f(2), f(3), f(13),
        f(4), f(5), f(6), f(7), f(8), f(9), f(10), f(11), ws);
    hipLaunchKernelGGL(k2_conv_proj, dim3(512), dim3(256), 0, stream,
        f(14), f(15), f(16), f(17), f(18), ws);
    hipLaunchKernelGGL(k3a_scan, dim3(256), dim3(256), 0, stream, f(19), ws);
    hipLaunchKernelGGL(k3c_scan_y, dim3(256), dim3(256), 0, stream, f(19), ws);
    hipLaunchKernelGGL(k4_out, dim3(512), dim3(256), 0, stream, ws, f(20), f(21), f(12),
        (float*)d_out);
}

// Round 4
// 247.892 us; speedup vs baseline: 1.3125x; 1.1864x over previous
//
#include <hip/hip_runtime.h>
#include <hip/hip_bf16.h>

#define L2E 1.4426950408889634f
#define LN2 0.6931471805599453f

__device__ __forceinline__ float fexp2(float x) { return __builtin_amdgcn_exp2f(x); }
__device__ __forceinline__ float flog2(float x) { return __builtin_amdgcn_logf(x); }
__device__ __forceinline__ int uniform(int x) { return __builtin_amdgcn_readfirstlane(x); }
__device__ __forceinline__ float sigmoidf_(float v) { return 1.f / (1.f + fexp2(-v * L2E)); }
__device__ __forceinline__ float softplusf_(float t) {
    return (t > 20.f) ? t : LN2 * flog2(1.f + fexp2(t * L2E));
}

// ---------------- workspace layout (floats), total 18,022,400 = 72.1 MB ----------------
constexpr size_t O_M   = 0;          // [32][1024] LN mean
constexpr size_t O_RS  = 32768;      // [32][1024] LN rstd
constexpr size_t O_G   = 65536;      // [32][128][1024] xi, later y_ssm
constexpr size_t O_Z   = 4259840;    // [32][128][1024] z
constexpr size_t O_XC  = 8454144;    // [32][128][1024] conv+silu out
constexpr size_t O_BM  = 12648448;   // [32][16][1024]
constexpr size_t O_CM  = 13172736;   // [32][16][1024]
constexpr size_t O_DTP = 13697024;   // [32][1024][4] dt-proj pre-softplus
constexpr size_t O_HP  = 13828096;   // [32][32][2][2048]: per-chunk P (→h_init) and E

// ================= K1: LN (in-block) + in-proj GEMM W[256,64] @ XN[64,1024] =================
// grid 2048 = 32 seq * 4 jb * 16 pb; block 256 (16 jt x 16 pt), tile 64j x 64p, K=64.
__global__ __launch_bounds__(256) void k1_ln_inproj(
    const float* __restrict__ x0, const float* __restrict__ x1,
    const float* __restrict__ x2, const float* __restrict__ x3,
    const float* __restrict__ win,
    const float* __restrict__ g1, const float* __restrict__ be1,
    const float* __restrict__ g2, const float* __restrict__ be2,
    const float* __restrict__ g3, const float* __restrict__ be3,
    const float* __restrict__ g4, const float* __restrict__ be4,
    float* __restrict__ ws)
{
    __shared__ float sX[64 * 68];
    __shared__ float sW[64 * 68];
    __shared__ float sM[64], sR[64];
    int bid = blockIdx.x;
    int seq = bid >> 6, jb = (bid >> 4) & 3, pb = bid & 15;
    int branch = seq >> 3, b = seq & 7;
    int tid = threadIdx.x;
    int lane = tid & 63;
    int wq = uniform(tid >> 6);
    const float* xin = (branch==0)?x0:(branch==1)?x1:(branch==2)?x2:x3;
    const float* gam = (branch==0)?g1:(branch==1)?g2:(branch==2)?g3:g4;
    const float* bet = (branch==0)?be1:(branch==1)?be2:(branch==2)?be3:be4;
    const float* xb = xin + (size_t)b * 65536;

    // stage raw X tile [c][p] and W^T tile [c][j]
#pragma unroll
    for (int r = 0; r < 16; ++r) {
        int row = r * 4 + wq;                         // uniform per wave
        sX[row * 68 + lane] = xb[(size_t)row * 1024 + pb * 64 + lane];
        sW[lane * 68 + row] = win[(size_t)(jb * 64 + row) * 64 + lane];
    }
    __syncthreads();
    // per-p LN stats (wave 0)
    if (tid < 64) {
        float sum = 0.f, sq = 0.f;
#pragma unroll
        for (int c = 0; c < 64; ++c) {
            float v = sX[c * 68 + tid];
            sum += v; sq += v * v;
        }
        float mean = sum * (1.f/64.f);
        float var  = sq * (1.f/64.f) - mean * mean;
        float rs   = rsqrtf(var + 1e-5f);
        sM[tid] = mean; sR[tid] = rs;
        if (jb == 0) {
            ws[O_M  + (size_t)seq * 1024 + pb * 64 + tid] = mean;
            ws[O_RS + (size_t)seq * 1024 + pb * 64 + tid] = rs;
        }
    }
    __syncthreads();
    // normalize in LDS
#pragma unroll
    for (int r = 0; r < 16; ++r) {
        int c = r * 4 + wq;
        float v = sX[c * 68 + lane];
        sX[c * 68 + lane] = (v - sM[lane]) * sR[lane] * gam[c] + bet[c];
    }
    __syncthreads();
    // micro-tile 4j x 4p
    int jt = tid >> 4, pt = tid & 15;
    float acc[4][4];
#pragma unroll
    for (int i = 0; i < 4; ++i)
#pragma unroll
        for (int j = 0; j < 4; ++j) acc[i][j] = 0.f;
    for (int c = 0; c < 64; ++c) {
        float4 wv = *(const float4*)&sW[c * 68 + jt * 4];
        float4 xv = *(const float4*)&sX[c * 68 + pt * 4];
        float w[4] = {wv.x, wv.y, wv.z, wv.w};
        float x[4] = {xv.x, xv.y, xv.z, xv.w};
#pragma unroll
        for (int i = 0; i < 4; ++i)
#pragma unroll
            for (int j = 0; j < 4; ++j) acc[i][j] += w[i] * x[j];
    }
    int p0 = pb * 64 + pt * 4;
    float* xi = ws + O_G + (size_t)seq * 131072;
    float* zz = ws + O_Z + (size_t)seq * 131072;
#pragma unroll
    for (int ji = 0; ji < 4; ++ji) {
        int j = jb * 64 + jt * 4 + ji;
        float4 v = make_float4(acc[ji][0], acc[ji][1], acc[ji][2], acc[ji][3]);
        if (j < 128) *(float4*)&xi[(size_t)j * 1024 + p0] = v;
        else         *(float4*)&zz[(size_t)(j - 128) * 1024 + p0] = v;
    }
}

// ================= K2: conv4 + SiLU + x-proj(128->36) =================
// grid 512 = 32 seq * 16 pt; block 256 = 4 waves x 64 p-lanes; each wave 32 d's.
__global__ __launch_bounds__(256) void k2_conv_proj(
    const float* __restrict__ wconv, const float* __restrict__ bconv,
    const float* __restrict__ wxp, float* __restrict__ ws)
{
    __shared__ float sWx[128 * 40];   // wxp^T [d][j], pad 40
    __shared__ float sAcc[36 * 64];
    int bid = blockIdx.x;
    int seq = bid >> 4, ptile = bid & 15;
    int tid = threadIdx.x;
    int lane = tid & 63;
    int wq = uniform(tid >> 6);
    int p = ptile * 64 + lane;

    for (int i = tid; i < 36 * 64; i += 256) sAcc[i] = 0.f;
    for (int i = tid; i < 36 * 128; i += 256) {
        int j = i >> 7, d = i & 127;
        sWx[d * 40 + j] = wxp[i];
    }
    __syncthreads();

    const float* xirow = ws + O_G  + (size_t)seq * 131072;
    float*       xcrow = ws + O_XC + (size_t)seq * 131072;
    float acc36[36];
#pragma unroll
    for (int j = 0; j < 36; ++j) acc36[j] = 0.f;

    for (int dd = 0; dd < 32; ++dd) {
        int d = wq * 32 + dd;                          // uniform
        const float* row = xirow + (size_t)d * 1024;
        float4 wc = *(const float4*)&wconv[d * 4];     // scalar
        float v = bconv[d];
        v += ((p >= 3) ? row[p-3] : 0.f) * wc.x;
        v += ((p >= 2) ? row[p-2] : 0.f) * wc.y;
        v += ((p >= 1) ? row[p-1] : 0.f) * wc.z;
        v += row[p] * wc.w;
        v = v * sigmoidf_(v);                          // silu
        xcrow[(size_t)d * 1024 + p] = v;
#pragma unroll
        for (int jq = 0; jq < 9; ++jq) {
            float4 w4 = *(const float4*)&sWx[d * 40 + jq * 4];   // wave-broadcast
            acc36[jq*4+0] += v * w4.x;
            acc36[jq*4+1] += v * w4.y;
            acc36[jq*4+2] += v * w4.z;
            acc36[jq*4+3] += v * w4.w;
        }
    }
#pragma unroll
    for (int j = 0; j < 36; ++j) atomicAdd(&sAcc[j * 64 + lane], acc36[j]);
    __syncthreads();
    if (tid < 64) {
        int pp = ptile * 64 + tid;
        float* Bm = ws + O_BM + (size_t)seq * 16384;
        float* Cm = ws + O_CM + (size_t)seq * 16384;
        for (int j = 0; j < 36; ++j) {
            float t = sAcc[j * 64 + tid];
            if (j < 4)       ws[O_DTP + ((size_t)seq * 1024 + pp) * 4 + j] = t;
            else if (j < 20) Bm[(size_t)(j - 4)  * 1024 + pp] = t;
            else             Cm[(size_t)(j - 20) * 1024 + pp] = t;
        }
    }
}

// ================= K3: chunk-parallel scan, 32 chunks of 32 steps =================
// thread -> d-pair 2*(tid>>2), s-quad 4*(tid&3): 8 states.
__device__ __forceinline__ void k3_preload(const float* wdt, const float* bdt,
                                           const float* alog, int d0, int s0,
                                           float4& wdt0, float4& wdt1, float& bdt0, float& bdt1,
                                           float* a2)
{
    wdt0 = *(const float4*)(wdt + d0 * 4);
    wdt1 = *(const float4*)(wdt + (d0 + 1) * 4);
    bdt0 = bdt[d0]; bdt1 = bdt[d0 + 1];
    float4 a0 = *(const float4*)(alog + d0 * 16 + s0);
    float4 a1 = *(const float4*)(alog + (d0 + 1) * 16 + s0);
    a2[0] = -fexp2(a0.x * L2E) * L2E; a2[1] = -fexp2(a0.y * L2E) * L2E;
    a2[2] = -fexp2(a0.z * L2E) * L2E; a2[3] = -fexp2(a0.w * L2E) * L2E;
    a2[4] = -fexp2(a1.x * L2E) * L2E; a2[5] = -fexp2(a1.y * L2E) * L2E;
    a2[6] = -fexp2(a1.z * L2E) * L2E; a2[7] = -fexp2(a1.w * L2E) * L2E;
}

// phase A: local scan (h0=0); emit per-chunk P = exp2(a2*sum_dt) and end-state E
__global__ __launch_bounds__(256) void k3a_scan(const float* __restrict__ wdt,
                                                const float* __restrict__ bdt,
                                                const float* __restrict__ alog,
                                                float* __restrict__ ws)
{
    __shared__ float sXC[128 * 33];
    __shared__ __align__(16) float sB[32 * 16];
    __shared__ __align__(16) float sDtp[32 * 4];
    int bid = blockIdx.x;
    int seq = bid >> 5, ch = bid & 31;
    int lb = ch * 32;
    int tid = threadIdx.x;
    int d0 = (tid >> 2) * 2, s0 = (tid & 3) * 4;

    float4 wdt0, wdt1; float bdt0, bdt1; float a2[8];
    k3_preload(wdt, bdt, alog, d0, s0, wdt0, wdt1, bdt0, bdt1, a2);

    const float* xcg = ws + O_XC + (size_t)seq * 131072;
    const float* Bmg = ws + O_BM + (size_t)seq * 16384;
    for (int i = tid; i < 4096; i += 256) {
        int d = i >> 5, li = i & 31;
        sXC[d * 33 + li] = xcg[(size_t)d * 1024 + lb + li];
    }
    for (int i = tid; i < 512; i += 256) {
        int s = i >> 5, li = i & 31;
        sB[li * 16 + s] = Bmg[(size_t)s * 1024 + lb + li];
    }
    if (tid < 128) sDtp[tid] = ws[O_DTP + ((size_t)seq * 1024 + lb + (tid >> 2)) * 4 + (tid & 3)];
    __syncthreads();

    float h[8];
#pragma unroll
    for (int i = 0; i < 8; ++i) h[i] = 0.f;
    float sdt0 = 0.f, sdt1 = 0.f;
    for (int li = 0; li < 32; ++li) {
        float4 q = *(const float4*)&sDtp[li * 4];
        float dt0 = softplusf_(bdt0 + q.x*wdt0.x + q.y*wdt0.y + q.z*wdt0.z + q.w*wdt0.w);
        float dt1 = softplusf_(bdt1 + q.x*wdt1.x + q.y*wdt1.y + q.z*wdt1.z + q.w*wdt1.w);
        float xc0 = sXC[d0 * 33 + li], xc1 = sXC[(d0 + 1) * 33 + li];
        float dx0 = dt0 * xc0, dx1 = dt1 * xc1;
        float4 Bv = *(const float4*)&sB[li * 16 + s0];
        float bv[4] = {Bv.x, Bv.y, Bv.z, Bv.w};
        sdt0 += dt0; sdt1 += dt1;
#pragma unroll
        for (int ss = 0; ss < 4; ++ss) {
            float e0 = fexp2(dt0 * a2[ss]);
            h[ss] = e0 * h[ss] + dx0 * bv[ss];
            float e1 = fexp2(dt1 * a2[4 + ss]);
            h[4 + ss] = e1 * h[4 + ss] + dx1 * bv[ss];
        }
    }
    float* hp = ws + O_HP + (size_t)(seq * 32 + ch) * 4096;
#pragma unroll
    for (int ss = 0; ss < 4; ++ss) {
        hp[d0 * 16 + s0 + ss]            = fexp2(a2[ss] * sdt0);
        hp[(d0 + 1) * 16 + s0 + ss]      = fexp2(a2[4 + ss] * sdt1);
        hp[2048 + d0 * 16 + s0 + ss]     = h[ss];
        hp[2048 + (d0 + 1) * 16 + s0 + ss] = h[4 + ss];
    }
}

// phase B: sequential prefix compose per seq; h_init overwrites the P slot.
__global__ __launch_bounds__(256) void k3b_compose(float* __restrict__ ws)
{
    int seq = blockIdx.x;
    int tid = threadIdx.x;
    int d0 = (tid >> 2) * 2, s0 = (tid & 3) * 4;
    int i0 = d0 * 16 + s0, i1 = (d0 + 1) * 16 + s0;
    float h[8];
#pragma unroll
    for (int i = 0; i < 8; ++i) h[i] = 0.f;
    float* hpb = ws + O_HP + (size_t)seq * 32 * 4096;
    for (int c = 0; c < 32; ++c) {
        float* hp = hpb + (size_t)c * 4096;
        float4 P0 = *(const float4*)&hp[i0];
        float4 P1 = *(const float4*)&hp[i1];
        float4 E0 = *(const float4*)&hp[2048 + i0];
        float4 E1 = *(const float4*)&hp[2048 + i1];
        *(float4*)&hp[i0] = make_float4(h[0], h[1], h[2], h[3]);
        *(float4*)&hp[i1] = make_float4(h[4], h[5], h[6], h[7]);
        h[0] = P0.x * h[0] + E0.x; h[1] = P0.y * h[1] + E0.y;
        h[2] = P0.z * h[2] + E0.z; h[3] = P0.w * h[3] + E0.w;
        h[4] = P1.x * h[4] + E1.x; h[5] = P1.y * h[5] + E1.y;
        h[6] = P1.z * h[6] + E1.z; h[7] = P1.w * h[7] + E1.w;
    }
}

// phase C: rescan from h_init, emit y into O_G
__global__ __launch_bounds__(256) void k3c_scan_y(const float* __restrict__ wdt,
                                                  const float* __restrict__ bdt,
                                                  const float* __restrict__ alog,
                                                  float* __restrict__ ws)
{
    __shared__ float sXC[128 * 33];
    __shared__ float sY[128 * 33];
    __shared__ __align__(16) float sB[32 * 16];
    __shared__ __align__(16) float sC[32 * 16];
    __shared__ __align__(16) float sDtp[32 * 4];
    int bid = blockIdx.x;
    int seq = bid >> 5, ch = bid & 31;
    int lb = ch * 32;
    int tid = threadIdx.x;
    int sq = tid & 3;
    int d0 = (tid >> 2) * 2, s0 = sq * 4;

    float4 wdt0, wdt1; float bdt0, bdt1; float a2[8];
    k3_preload(wdt, bdt, alog, d0, s0, wdt0, wdt1, bdt0, bdt1, a2);

    const float* xcg = ws + O_XC + (size_t)seq * 131072;
    const float* Bmg = ws + O_BM + (size_t)seq * 16384;
    const float* Cmg = ws + O_CM + (size_t)seq * 16384;
    float*       gg  = ws + O_G  + (size_t)seq * 131072;
    for (int i = tid; i < 4096; i += 256) {
        int d = i >> 5, li = i & 31;
        sXC[d * 33 + li] = xcg[(size_t)d * 1024 + lb + li];
    }
    for (int i = tid; i < 512; i += 256) {
        int s = i >> 5, li = i & 31;
        sB[li * 16 + s] = Bmg[(size_t)s * 1024 + lb + li];
        sC[li * 16 + s] = Cmg[(size_t)s * 1024 + lb + li];
    }
    if (tid < 128) sDtp[tid] = ws[O_DTP + ((size_t)seq * 1024 + lb + (tid >> 2)) * 4 + (tid & 3)];

    const float* hp = ws + O_HP + (size_t)(seq * 32 + ch) * 4096;
    float4 H0 = *(const float4*)&hp[d0 * 16 + s0];
    float4 H1 = *(const float4*)&hp[(d0 + 1) * 16 + s0];
    float h[8] = {H0.x, H0.y, H0.z, H0.w, H1.x, H1.y, H1.z, H1.w};
    __syncthreads();

    for (int li = 0; li < 32; ++li) {
        float4 q = *(const float4*)&sDtp[li * 4];
        float dt0 = softplusf_(bdt0 + q.x*wdt0.x + q.y*wdt0.y + q.z*wdt0.z + q.w*wdt0.w);
        float dt1 = softplusf_(bdt1 + q.x*wdt1.x + q.y*wdt1.y + q.z*wdt1.z + q.w*wdt1.w);
        float xc0 = sXC[d0 * 33 + li], xc1 = sXC[(d0 + 1) * 33 + li];
        float dx0 = dt0 * xc0, dx1 = dt1 * xc1;
        float4 Bv = *(const float4*)&sB[li * 16 + s0];
        float4 Cv = *(const float4*)&sC[li * 16 + s0];
        float bv[4] = {Bv.x, Bv.y, Bv.z, Bv.w};
        float cv[4] = {Cv.x, Cv.y, Cv.z, Cv.w};
        float acc0 = 0.f, acc1 = 0.f;
#pragma unroll
        for (int ss = 0; ss < 4; ++ss) {
            float e0 = fexp2(dt0 * a2[ss]);
            h[ss] = e0 * h[ss] + dx0 * bv[ss];
            acc0 += h[ss] * cv[ss];
            float e1 = fexp2(dt1 * a2[4 + ss]);
            h[4 + ss] = e1 * h[4 + ss] + dx1 * bv[ss];
            acc1 += h[4 + ss] * cv[ss];
        }
        acc0 += __shfl_xor(acc0, 1); acc0 += __shfl_xor(acc0, 2);
        acc1 += __shfl_xor(acc1, 1); acc1 += __shfl_xor(acc1, 2);
        if (sq == 0) {
            sY[d0 * 33 + li]       = acc0;
            sY[(d0 + 1) * 33 + li] = acc1;
        }
    }
    __syncthreads();
    for (int i = tid; i < 4096; i += 256) {
        int d = i >> 5, li = i & 31;
        gg[(size_t)d * 1024 + lb + li] = sY[d * 33 + li];
    }
}

// ================= K4: gate + out-proj Wout[64,128] @ G[128,1024] + skip =================
// grid 512 = 32 seq * 16 pb; block 256 (16 ct x 16 pt), tile 64c x 64p, K=128 in 2 halves.
__global__ __launch_bounds__(256) void k4_out(
    const float* __restrict__ x0, const float* __restrict__ x1,
    const float* __restrict__ x2, const float* __restrict__ x3,
    const float* __restrict__ g1, const float* __restrict__ be1,
    const float* __restrict__ g2, const float* __restrict__ be2,
    const float* __restrict__ g3, const float* __restrict__ be3,
    const float* __restrict__ g4, const float* __restrict__ be4,
    const float* __restrict__ dpar, const float* __restrict__ woutp,
    const float* __restrict__ skipp, const float* __restrict__ ws,
    float* __restrict__ out)
{
    __shared__ float sG[64 * 68];
    __shared__ float sW[64 * 68];
    int bid = blockIdx.x;
    int seq = bid >> 4, pb = bid & 15;
    int branch = seq >> 3, b = seq & 7;
    int tid = threadIdx.x;
    int lane = tid & 63;
    int wq = uniform(tid >> 6);
    int ct = tid >> 4, pt = tid & 15;

    const float* ys = ws + O_G  + (size_t)seq * 131072;
    const float* zz = ws + O_Z  + (size_t)seq * 131072;
    const float* xc = ws + O_XC + (size_t)seq * 131072;

    float acc[4][4];
#pragma unroll
    for (int i = 0; i < 4; ++i)
#pragma unroll
        for (int j = 0; j < 4; ++j) acc[i][j] = 0.f;

    for (int hf = 0; hf < 2; ++hf) {
#pragma unroll
        for (int r = 0; r < 16; ++r) {
            int row = r * 4 + wq;                    // uniform
            sW[lane * 68 + row] = woutp[(size_t)row * 128 + hf * 64 + lane];
            int d = hf * 64 + row;
            size_t off = (size_t)d * 1024 + pb * 64 + lane;
            float yv = ys[off], zv = zz[off], xcv = xc[off];
            sG[row * 68 + lane] = (yv + dpar[d] * xcv) * (zv * sigmoidf_(zv));
        }
        __syncthreads();
        for (int dl = 0; dl < 64; ++dl) {
            float4 wv = *(const float4*)&sW[dl * 68 + ct * 4];
            float4 gv = *(const float4*)&sG[dl * 68 + pt * 4];
            float w[4] = {wv.x, wv.y, wv.z, wv.w};
            float g[4] = {gv.x, gv.y, gv.z, gv.w};
#pragma unroll
            for (int i = 0; i < 4; ++i)
#pragma unroll
                for (int j = 0; j < 4; ++j) acc[i][j] += w[i] * g[j];
        }
        __syncthreads();
    }

    // epilogue: + skip * xn (recomputed from x and stored stats)
    const float* xin = (branch==0)?x0:(branch==1)?x1:(branch==2)?x2:x3;
    const float* gam = (branch==0)?g1:(branch==1)?g2:(branch==2)?g3:g4;
    const float* bet = (branch==0)?be1:(branch==1)?be2:(branch==2)?be3:be4;
    const float* xb = xin + (size_t)b * 65536;
    int p0 = pb * 64 + pt * 4;
    float skipv = skipp[0];
    float4 m4 = *(const float4*)&ws[O_M  + (size_t)seq * 1024 + p0];
    float4 r4 = *(const float4*)&ws[O_RS + (size_t)seq * 1024 + p0];
    float mm[4] = {m4.x, m4.y, m4.z, m4.w};
    float rr[4] = {r4.x, r4.y, r4.z, r4.w};
#pragma unroll
    for (int ci = 0; ci < 4; ++ci) {
        int c = ct * 4 + ci;
        float4 xv = *(const float4*)&xb[(size_t)c * 1024 + p0];
        float xvv[4] = {xv.x, xv.y, xv.z, xv.w};
        float gc = gam[c], bc = bet[c];
        float o[4];
#pragma unroll
        for (int pi = 0; pi < 4; ++pi) {
            float xn = (xvv[pi] - mm[pi]) * rr[pi] * gc + bc;
            o[pi] = acc[ci][pi] + skipv * xn;
        }
        *(float4*)&out[((size_t)b * 256 + branch * 64 + c) * 1024 + p0] =
            make_float4(o[0], o[1], o[2], o[3]);
    }
}

// ---------------- launch ----------------
extern "C" void kernel_launch(void* const* d_in, const int* in_sizes, int n_in,
                              void* d_out, int out_size, void* d_ws, size_t ws_size,
                              hipStream_t stream) {
    float* ws = (float*)d_ws;
    auto f = [&](int i) { return (const float*)d_in[i]; };
    hipLaunchKernelGGL(k1_ln_inproj, dim3(2048), dim3(256), 0, stream,
        f(0), f(1), f(2), f(3), f(13),
        f(4), f(5), f(6), f(7), f(8), f(9), f(10), f(11), ws);
    hipLaunchKernelGGL(k2_conv_proj, dim3(512), dim3(256), 0, stream,
        f(14), f(15), f(16), ws);
    hipLaunchKernelGGL(k3a_scan, dim3(1024), dim3(256), 0, stream, f(17), f(18), f(19), ws);
    hipLaunchKernelGGL(k3b_compose, dim3(32), dim3(256), 0, stream, ws);
    hipLaunchKernelGGL(k3c_scan_y, dim3(1024), dim3(256), 0, stream, f(17), f(18), f(19), ws);
    hipLaunchKernelGGL(k4_out, dim3(512), dim3(256), 0, stream,
        f(0), f(1), f(2), f(3),
        f(4), f(5), f(6), f(7), f(8), f(9), f(10), f(11),
        f(20), f(21), f(12), ws, (float*)d_out);
}